// Round 12
// baseline (353.897 us; speedup 1.0000x reference)
//
#include <hip/hip_runtime.h>
#include <hip/hip_bf16.h>
#include <cstdint>
#include <cstddef>

// Problem constants (from reference): N=50000, E=600000, D=128, C=40, M=25000
#define DIM 128

typedef __attribute__((ext_vector_type(8))) short bf16x8;   // 8 bf16 = 4 VGPRs
typedef __attribute__((ext_vector_type(4))) float f32x4;

__device__ __forceinline__ unsigned short f2bf(float f) {
    __hip_bfloat16 h = __float2bfloat16(f);   // RN-even
    return *(unsigned short*)&h;
}
__device__ __forceinline__ unsigned pack_bf2(float a, float b) {
    return (unsigned)f2bf(a) | ((unsigned)f2bf(b) << 16);
}
// dword holding 2 bf16 -> two fp32: lo = u<<16, hi = u & 0xffff0000
__device__ __forceinline__ float bflo(unsigned u) { return __uint_as_float(u << 16); }
__device__ __forceinline__ float bfhi(unsigned u) { return __uint_as_float(u & 0xffff0000u); }

union U4B8 { uint4 q; bf16x8 v; };

// ---------------------------------------------------------------------------
// CSR build: count in-degrees, parallel scan (+dinv fused), fill column lists
// ---------------------------------------------------------------------------
__global__ void k_count(const int* __restrict__ dst, int* __restrict__ count, int e) {
    int i = blockIdx.x * 256 + threadIdx.x;
    if (i < e) atomicAdd(&count[dst[i]], 1);
}

__global__ __launch_bounds__(1024)
void k_scanA(const int* __restrict__ count, int* __restrict__ partial,
             int* __restrict__ bsum, float* __restrict__ dinv, int n) {
    __shared__ int wsum[16];
    int tid = threadIdx.x, lane = tid & 63, wid = tid >> 6;
    int i = blockIdx.x * 1024 + tid;
    int v = (i < n) ? count[i] : 0;
    if (i < n) dinv[i] = rsqrtf(1.0f + (float)v);   // deg includes self-loop
    int x = v;
    #pragma unroll
    for (int off = 1; off < 64; off <<= 1) {
        int y = __shfl_up(x, off, 64);
        if (lane >= off) x += y;
    }
    if (lane == 63) wsum[wid] = x;
    __syncthreads();
    int waveoff = 0, total = 0;
    #pragma unroll
    for (int w = 0; w < 16; ++w) {
        int s = wsum[w];
        if (w < wid) waveoff += s;
        total += s;
    }
    if (i < n) partial[i] = x + waveoff;            // block-local inclusive
    if (tid == 0) bsum[blockIdx.x] = total;
}

__global__ __launch_bounds__(1024)
void k_scanB(const int* __restrict__ count, const int* __restrict__ partial,
             const int* __restrict__ bsum, int* __restrict__ row_ptr,
             int* __restrict__ cursor, int n, int nb) {
    __shared__ int s_off;
    int tid = threadIdx.x;
    if (tid < 64) {
        int carry = 0;
        for (int base = 0; base < nb; base += 64) {
            int idx = base + tid;
            int v = (idx < nb && idx < blockIdx.x) ? bsum[idx] : 0;
            #pragma unroll
            for (int off = 32; off > 0; off >>= 1) v += __shfl_xor(v, off, 64);
            carry += v;
        }
        if (tid == 0) s_off = carry;
    }
    __syncthreads();
    int off = s_off;
    int i = blockIdx.x * 1024 + tid;
    if (i < n) {
        int inc = partial[i] + off;
        row_ptr[i + 1] = inc;
        cursor[i] = inc - count[i];
    }
    if (blockIdx.x == 0 && tid == 0) row_ptr[0] = 0;
}

__global__ void k_fill(const int* __restrict__ src, const int* __restrict__ dst,
                       int* __restrict__ cursor, int* __restrict__ col, int e) {
    int i = blockIdx.x * 256 + threadIdx.x;
    if (i < e) {
        int d = dst[i];
        int pos = atomicAdd(&cursor[d], 1);
        col[pos] = src[i];
    }
}

// ---------------------------------------------------------------------------
// One-shot packing (merged: Wpk + WhP + whs + count zeroing, one launch —
// replaces the hipMemsetAsync dispatch; runs first in the stream).
// Wpk[(((mat*8+nt)*4+kc)*64 + lane)*8 + j] = bf16(W[k][n])
//   k = kc*32 + (lane>>4)*8 + j,  n = nt*16 + (lane&15).
// ---------------------------------------------------------------------------
__global__ void k_pack(const float* __restrict__ W0, const float* __restrict__ W1,
                       const float* __restrict__ W2, const float* __restrict__ W3,
                       const float* __restrict__ Wh,
                       unsigned short* __restrict__ Wpk,
                       unsigned short* __restrict__ WhP,
                       float* __restrict__ whs, int* __restrict__ count,
                       int C, int n) {
    const int NW = 4 * DIM * DIM;        // 65536
    const int NH = 3 * 4 * 64 * 8;       // 6144
    int g = blockIdx.x * 256 + threadIdx.x;
    if (g < n) count[g] = 0;             // replaces hipMemsetAsync(count)
    if (g < NW) {
        int j   = g & 7;
        int ln  = (g >> 3) & 63;
        int kc  = (g >> 9) & 3;
        int nt  = (g >> 11) & 7;
        int mat = g >> 14;
        const float* W = (mat == 0) ? W0 : (mat == 1) ? W1 : (mat == 2) ? W2 : W3;
        int k = kc * 32 + (ln >> 4) * 8 + j;
        int nc = nt * 16 + (ln & 15);
        Wpk[g] = f2bf(W[k * DIM + nc]);
    } else if (g < NW + NH) {
        int gg = g - NW;
        int j  = gg & 7;
        int ln = (gg >> 3) & 63;
        int kc = (gg >> 9) & 3;
        int nt = gg >> 11;               // 0..2
        int k  = kc * 32 + (ln >> 4) * 8 + j;
        int nc = nt * 16 + (ln & 15);
        WhP[gg] = (nc < C) ? f2bf(Wh[k * C + nc]) : (unsigned short)0;
    } else if (g < NW + NH + 64) {
        int c = g - NW - NH;
        if (c < C) {
            float s = 0.f;
            for (int d = 0; d < DIM; ++d) s += Wh[d * C + c];
            whs[c] = s;
        }
    }
}

// ---------------------------------------------------------------------------
// MFMA matmul, fp32 input (layer 0): H'[N,128](bf16) = dinv[r]*(in @ W).
// Wave = 16-row x 128-col strip: 8 n-tiles x 4 kc = 32 mfma_f32_16x16x32_bf16.
// No LDS, no barriers. Layouts (m89/m91-verified).
// ---------------------------------------------------------------------------
__global__ __launch_bounds__(256)
void k_matmul_f(const float* __restrict__ in, const unsigned short* __restrict__ Wpk,
                const float* __restrict__ dinv, unsigned short* __restrict__ outp, int n) {
    int wv   = threadIdx.x >> 6;
    int lane = threadIdx.x & 63;
    int r0   = blockIdx.x * 64 + wv * 16;
    int m    = lane & 15;
    int quad = lane >> 4;

    bf16x8 afr[4];
    int arow = r0 + m;
    bool rowok = arow < n;
    const float* ap = in + (size_t)arow * DIM + quad * 8;
    #pragma unroll
    for (int kc = 0; kc < 4; ++kc) {
        float4 p0, p1;
        if (rowok) {
            p0 = *(const float4*)(ap + kc * 32);
            p1 = *(const float4*)(ap + kc * 32 + 4);
        } else {
            p0.x = p0.y = p0.z = p0.w = 0.f;
            p1.x = p1.y = p1.z = p1.w = 0.f;
        }
        union { bf16x8 v; unsigned short u[8]; } a;
        a.u[0] = f2bf(p0.x); a.u[1] = f2bf(p0.y);
        a.u[2] = f2bf(p0.z); a.u[3] = f2bf(p0.w);
        a.u[4] = f2bf(p1.x); a.u[5] = f2bf(p1.y);
        a.u[6] = f2bf(p1.z); a.u[7] = f2bf(p1.w);
        afr[kc] = a.v;
    }

    float dsc[4];
    #pragma unroll
    for (int t = 0; t < 4; ++t) {
        int r = r0 + quad * 4 + t;
        dsc[t] = (r < n) ? dinv[r] : 0.f;
    }

    const uint4* wp = (const uint4*)Wpk;
    #pragma unroll
    for (int nt = 0; nt < 8; ++nt) {
        f32x4 acc = {0.f, 0.f, 0.f, 0.f};
        #pragma unroll
        for (int kc = 0; kc < 4; ++kc) {
            U4B8 b; b.q = wp[(nt * 4 + kc) * 64 + lane];
            acc = __builtin_amdgcn_mfma_f32_16x16x32_bf16(afr[kc], b.v, acc, 0, 0, 0);
        }
        int colb = nt * 16 + m;
        #pragma unroll
        for (int t = 0; t < 4; ++t) {
            int r = r0 + quad * 4 + t;
            if (r < n)
                outp[(size_t)r * DIM + colb] = f2bf(dsc[t] * acc[t]);
        }
    }
}

// Same, bf16 input (layers 1-3): A-frag is a single uint4 load per K-chunk.
__global__ __launch_bounds__(256)
void k_matmul_b(const unsigned short* __restrict__ in, const unsigned short* __restrict__ Wpk,
                const float* __restrict__ dinv, unsigned short* __restrict__ outp, int n) {
    int wv   = threadIdx.x >> 6;
    int lane = threadIdx.x & 63;
    int r0   = blockIdx.x * 64 + wv * 16;
    int m    = lane & 15;
    int quad = lane >> 4;

    bf16x8 afr[4];
    int arow = r0 + m;
    bool rowok = arow < n;
    const uint4* in16 = (const uint4*)in;   // one row = 16 uint4
    #pragma unroll
    for (int kc = 0; kc < 4; ++kc) {
        U4B8 a;
        if (rowok) a.q = in16[(size_t)arow * 16 + kc * 4 + quad];
        else { a.q.x = a.q.y = a.q.z = a.q.w = 0u; }
        afr[kc] = a.v;
    }

    float dsc[4];
    #pragma unroll
    for (int t = 0; t < 4; ++t) {
        int r = r0 + quad * 4 + t;
        dsc[t] = (r < n) ? dinv[r] : 0.f;
    }

    const uint4* wp = (const uint4*)Wpk;
    #pragma unroll
    for (int nt = 0; nt < 8; ++nt) {
        f32x4 acc = {0.f, 0.f, 0.f, 0.f};
        #pragma unroll
        for (int kc = 0; kc < 4; ++kc) {
            U4B8 b; b.q = wp[(nt * 4 + kc) * 64 + lane];
            acc = __builtin_amdgcn_mfma_f32_16x16x32_bf16(afr[kc], b.v, acc, 0, 0, 0);
        }
        int colb = nt * 16 + m;
        #pragma unroll
        for (int t = 0; t < 4; ++t) {
            int r = r0 + quad * 4 + t;
            if (r < n)
                outp[(size_t)r * DIM + colb] = f2bf(dsc[t] * acc[t]);
        }
    }
}

// ---------------------------------------------------------------------------
// Propagation, quarter-wave gather, 4-deep pipeline: quarter q issues edges
// j, j+4, j+8, j+12 back-to-back (stride 16); avg degree 12 -> whole node's
// gather in flight in one iteration. Self-row/bias/addin LOADS hoisted above
// the loop (overlap the gathers).
// *** ROUND-10 BUG, NOW FIXED: the self-row CONTRIBUTION must be added AFTER
// the cross-quarter shuffle reduction — adding it per-quarter pre-shuffle
// counts the self-loop 4x (absmax blew up to ~18). Load early, add late. ***
//   cell = di*(sum_edges H'[s] + H'[node]) + bscale*bias; relu; (+addin)
// addin==outp (in-place) allowed: each wave only touches its own row.
// ---------------------------------------------------------------------------
__global__ __launch_bounds__(256)
void k_prop(const unsigned short* __restrict__ h, const int* __restrict__ row_ptr,
            const int* __restrict__ col, const float* __restrict__ dinv,
            const float* __restrict__ bias, float bscale,
            const unsigned short* addin, unsigned short* outp, int n) {
    int node = (blockIdx.x * 256 + threadIdx.x) >> 6;
    int lane = threadIdx.x & 63;
    if (node >= n) return;
    int beg = row_ptr[node], end = row_ptr[node + 1];
    float di = dinv[node];
    int qid = lane >> 4;            // which quarter
    int fo  = lane & 15;            // feature octet: features 8*fo .. 8*fo+7
    const uint4* h16 = (const uint4*)h;   // one row = 16 uint4
    const uint4 z4 = {0u, 0u, 0u, 0u};

    // hoisted node-local LOADS (in flight during the edge gather)
    uint4 sd = h16[((unsigned)node << 4) | fo];
    const float4* b4 = (const float4*)bias;
    float4 bA = b4[2 * fo], bB = b4[2 * fo + 1];
    uint4 av = z4;
    if (addin) av = ((const uint4*)addin)[(size_t)node * 16 + fo];

    float aL0 = 0.f, aH0 = 0.f, aL1 = 0.f, aH1 = 0.f;
    float aL2 = 0.f, aH2 = 0.f, aL3 = 0.f, aH3 = 0.f;
    float bL0 = 0.f, bH0 = 0.f, bL1 = 0.f, bH1 = 0.f;
    float bL2 = 0.f, bH2 = 0.f, bL3 = 0.f, bH3 = 0.f;
    int j = beg + qid;
    int s0 = (j      < end) ? col[j]      : -1;
    int s1 = (j + 4  < end) ? col[j + 4]  : -1;
    int s2 = (j + 8  < end) ? col[j + 8]  : -1;
    int s3 = (j + 12 < end) ? col[j + 12] : -1;
    while (s0 >= 0) {
        uint4 d0 = h16[((unsigned)s0 << 4) | fo];
        uint4 d1 = (s1 >= 0) ? h16[((unsigned)s1 << 4) | fo] : z4;
        uint4 d2 = (s2 >= 0) ? h16[((unsigned)s2 << 4) | fo] : z4;
        uint4 d3 = (s3 >= 0) ? h16[((unsigned)s3 << 4) | fo] : z4;
        j += 16;
        s0 = (j      < end) ? col[j]      : -1;   // prefetch next 4
        s1 = (j + 4  < end) ? col[j + 4]  : -1;
        s2 = (j + 8  < end) ? col[j + 8]  : -1;
        s3 = (j + 12 < end) ? col[j + 12] : -1;
        aL0 += bflo(d0.x); aH0 += bfhi(d0.x);
        aL1 += bflo(d0.y); aH1 += bfhi(d0.y);
        aL2 += bflo(d0.z); aH2 += bfhi(d0.z);
        aL3 += bflo(d0.w); aH3 += bfhi(d0.w);
        bL0 += bflo(d1.x); bH0 += bfhi(d1.x);
        bL1 += bflo(d1.y); bH1 += bfhi(d1.y);
        bL2 += bflo(d1.z); bH2 += bfhi(d1.z);
        bL3 += bflo(d1.w); bH3 += bfhi(d1.w);
        aL0 += bflo(d2.x); aH0 += bfhi(d2.x);
        aL1 += bflo(d2.y); aH1 += bfhi(d2.y);
        aL2 += bflo(d2.z); aH2 += bfhi(d2.z);
        aL3 += bflo(d2.w); aH3 += bfhi(d2.w);
        bL0 += bflo(d3.x); bH0 += bfhi(d3.x);
        bL1 += bflo(d3.y); bH1 += bfhi(d3.y);
        bL2 += bflo(d3.z); bH2 += bfhi(d3.z);
        bL3 += bflo(d3.w); bH3 += bfhi(d3.w);
    }
    aL0 += bL0; aH0 += bH0; aL1 += bL1; aH1 += bH1;
    aL2 += bL2; aH2 += bH2; aL3 += bL3; aH3 += bH3;
    // combine the 4 quarters (wave fully reconverged here)
    aL0 += __shfl_xor(aL0, 16, 64); aL0 += __shfl_xor(aL0, 32, 64);
    aH0 += __shfl_xor(aH0, 16, 64); aH0 += __shfl_xor(aH0, 32, 64);
    aL1 += __shfl_xor(aL1, 16, 64); aL1 += __shfl_xor(aL1, 32, 64);
    aH1 += __shfl_xor(aH1, 16, 64); aH1 += __shfl_xor(aH1, 32, 64);
    aL2 += __shfl_xor(aL2, 16, 64); aL2 += __shfl_xor(aL2, 32, 64);
    aH2 += __shfl_xor(aH2, 16, 64); aH2 += __shfl_xor(aH2, 32, 64);
    aL3 += __shfl_xor(aL3, 16, 64); aL3 += __shfl_xor(aL3, 32, 64);
    aH3 += __shfl_xor(aH3, 16, 64); aH3 += __shfl_xor(aH3, 32, 64);
    // self-loop AFTER the reduction (counted exactly once):
    aL0 += bflo(sd.x); aH0 += bfhi(sd.x);
    aL1 += bflo(sd.y); aH1 += bfhi(sd.y);
    aL2 += bflo(sd.z); aH2 += bfhi(sd.z);
    aL3 += bflo(sd.w); aH3 += bfhi(sd.w);
    if (lane < 16) {                // fo lanes of quarter 0 store the row
        float r0x = fmaxf(fmaf(bscale, bA.x, di * aL0), 0.f) + bflo(av.x);
        float r0y = fmaxf(fmaf(bscale, bA.y, di * aH0), 0.f) + bfhi(av.x);
        float r0z = fmaxf(fmaf(bscale, bA.z, di * aL1), 0.f) + bflo(av.y);
        float r0w = fmaxf(fmaf(bscale, bA.w, di * aH1), 0.f) + bfhi(av.y);
        float r1x = fmaxf(fmaf(bscale, bB.x, di * aL2), 0.f) + bflo(av.z);
        float r1y = fmaxf(fmaf(bscale, bB.y, di * aH2), 0.f) + bfhi(av.z);
        float r1z = fmaxf(fmaf(bscale, bB.z, di * aL3), 0.f) + bflo(av.w);
        float r1w = fmaxf(fmaf(bscale, bB.w, di * aH3), 0.f) + bfhi(av.w);
        uint4 o;
        o.x = pack_bf2(r0x, r0y);
        o.y = pack_bf2(r0z, r0w);
        o.z = pack_bf2(r1x, r1y);
        o.w = pack_bf2(r1z, r1w);
        ((uint4*)outp)[(size_t)node * 16 + fo] = o;
    }
}

// ---------------------------------------------------------------------------
// Gather cell3 for label rows only; same 4-deep pipelined gather (self-row
// added AFTER the reduction); writes compact bf16 V[m,128] + L[m].
// ---------------------------------------------------------------------------
__global__ __launch_bounds__(256)
void k_prop_v(const unsigned short* __restrict__ h, const int* __restrict__ row_ptr,
              const int* __restrict__ col, const float* __restrict__ dinv,
              const float* __restrict__ bias, float bscale,
              const int* __restrict__ labels,
              unsigned short* __restrict__ V, float* __restrict__ Lbuf, int m_total) {
    int m = (blockIdx.x * 256 + threadIdx.x) >> 6;
    int lane = threadIdx.x & 63;
    if (m >= m_total) return;
    int node = labels[m];
    int beg = row_ptr[node], end = row_ptr[node + 1];
    float di = dinv[node];
    int qid = lane >> 4, fo = lane & 15;
    const uint4* h16 = (const uint4*)h;
    const uint4 z4 = {0u, 0u, 0u, 0u};

    uint4 sd = h16[((unsigned)node << 4) | fo];   // hoisted load, added late
    const float4* b4 = (const float4*)bias;
    float4 bA = b4[2 * fo], bB = b4[2 * fo + 1];

    float aL0 = 0.f, aH0 = 0.f, aL1 = 0.f, aH1 = 0.f;
    float aL2 = 0.f, aH2 = 0.f, aL3 = 0.f, aH3 = 0.f;
    float bL0 = 0.f, bH0 = 0.f, bL1 = 0.f, bH1 = 0.f;
    float bL2 = 0.f, bH2 = 0.f, bL3 = 0.f, bH3 = 0.f;
    int j = beg + qid;
    int s0 = (j      < end) ? col[j]      : -1;
    int s1 = (j + 4  < end) ? col[j + 4]  : -1;
    int s2 = (j + 8  < end) ? col[j + 8]  : -1;
    int s3 = (j + 12 < end) ? col[j + 12] : -1;
    while (s0 >= 0) {
        uint4 d0 = h16[((unsigned)s0 << 4) | fo];
        uint4 d1 = (s1 >= 0) ? h16[((unsigned)s1 << 4) | fo] : z4;
        uint4 d2 = (s2 >= 0) ? h16[((unsigned)s2 << 4) | fo] : z4;
        uint4 d3 = (s3 >= 0) ? h16[((unsigned)s3 << 4) | fo] : z4;
        j += 16;
        s0 = (j      < end) ? col[j]      : -1;
        s1 = (j + 4  < end) ? col[j + 4]  : -1;
        s2 = (j + 8  < end) ? col[j + 8]  : -1;
        s3 = (j + 12 < end) ? col[j + 12] : -1;
        aL0 += bflo(d0.x); aH0 += bfhi(d0.x);
        aL1 += bflo(d0.y); aH1 += bfhi(d0.y);
        aL2 += bflo(d0.z); aH2 += bfhi(d0.z);
        aL3 += bflo(d0.w); aH3 += bfhi(d0.w);
        bL0 += bflo(d1.x); bH0 += bfhi(d1.x);
        bL1 += bflo(d1.y); bH1 += bfhi(d1.y);
        bL2 += bflo(d1.z); bH2 += bfhi(d1.z);
        bL3 += bflo(d1.w); bH3 += bfhi(d1.w);
        aL0 += bflo(d2.x); aH0 += bfhi(d2.x);
        aL1 += bflo(d2.y); aH1 += bfhi(d2.y);
        aL2 += bflo(d2.z); aH2 += bfhi(d2.z);
        aL3 += bflo(d2.w); aH3 += bfhi(d2.w);
        bL0 += bflo(d3.x); bH0 += bfhi(d3.x);
        bL1 += bflo(d3.y); bH1 += bfhi(d3.y);
        bL2 += bflo(d3.z); bH2 += bfhi(d3.z);
        bL3 += bflo(d3.w); bH3 += bfhi(d3.w);
    }
    aL0 += bL0; aH0 += bH0; aL1 += bL1; aH1 += bH1;
    aL2 += bL2; aH2 += bH2; aL3 += bL3; aH3 += bH3;
    aL0 += __shfl_xor(aL0, 16, 64); aL0 += __shfl_xor(aL0, 32, 64);
    aH0 += __shfl_xor(aH0, 16, 64); aH0 += __shfl_xor(aH0, 32, 64);
    aL1 += __shfl_xor(aL1, 16, 64); aL1 += __shfl_xor(aL1, 32, 64);
    aH1 += __shfl_xor(aH1, 16, 64); aH1 += __shfl_xor(aH1, 32, 64);
    aL2 += __shfl_xor(aL2, 16, 64); aL2 += __shfl_xor(aL2, 32, 64);
    aH2 += __shfl_xor(aH2, 16, 64); aH2 += __shfl_xor(aH2, 32, 64);
    aL3 += __shfl_xor(aL3, 16, 64); aL3 += __shfl_xor(aL3, 32, 64);
    aH3 += __shfl_xor(aH3, 16, 64); aH3 += __shfl_xor(aH3, 32, 64);
    // self-loop AFTER the reduction (counted exactly once):
    aL0 += bflo(sd.x); aH0 += bfhi(sd.x);
    aL1 += bflo(sd.y); aH1 += bfhi(sd.y);
    aL2 += bflo(sd.z); aH2 += bfhi(sd.z);
    aL3 += bflo(sd.w); aH3 += bfhi(sd.w);
    float v0 = fmaf(bscale, bA.x, di * aL0);
    float v1 = fmaf(bscale, bA.y, di * aH0);
    float v2 = fmaf(bscale, bA.z, di * aL1);
    float v3 = fmaf(bscale, bA.w, di * aH1);
    float v4 = fmaf(bscale, bB.x, di * aL2);
    float v5 = fmaf(bscale, bB.y, di * aH2);
    float v6 = fmaf(bscale, bB.z, di * aL3);
    float v7 = fmaf(bscale, bB.w, di * aH3);
    // logsumexp over 128 features (16 distinct fo groups; quarters duplicate)
    float mx = fmaxf(fmaxf(fmaxf(v0, v1), fmaxf(v2, v3)),
                     fmaxf(fmaxf(v4, v5), fmaxf(v6, v7)));
    #pragma unroll
    for (int off = 8; off > 0; off >>= 1) mx = fmaxf(mx, __shfl_xor(mx, off, 64));
    float se = expf(v0 - mx) + expf(v1 - mx) + expf(v2 - mx) + expf(v3 - mx)
             + expf(v4 - mx) + expf(v5 - mx) + expf(v6 - mx) + expf(v7 - mx);
    #pragma unroll
    for (int off = 8; off > 0; off >>= 1) se += __shfl_xor(se, off, 64);
    float L = mx + logf(se);
    if (lane < 16) {
        uint4 o;
        o.x = pack_bf2(v0, v1);
        o.y = pack_bf2(v2, v3);
        o.z = pack_bf2(v4, v5);
        o.w = pack_bf2(v6, v7);
        ((uint4*)V)[(size_t)m * 16 + fo] = o;
    }
    if (lane == 0) Lbuf[m] = L;
}

// ---------------------------------------------------------------------------
// Head GEMM (MFMA): out[m,c] = V[m,:]@Wh[:,c] - L[m]*whs[c] + bh[c], c<C.
// Wave = 16 rows; 3 n-tiles (48 padded cols) x 4 kc = 12 MFMAs.
// ---------------------------------------------------------------------------
__global__ __launch_bounds__(256)
void k_head(const unsigned short* __restrict__ V, const float* __restrict__ Lbuf,
            const unsigned short* __restrict__ WhP, const float* __restrict__ whs,
            const float* __restrict__ bh, float* __restrict__ outp,
            int m_total, int C) {
    int wv   = threadIdx.x >> 6;
    int lane = threadIdx.x & 63;
    int r0   = blockIdx.x * 64 + wv * 16;
    int m    = lane & 15;
    int quad = lane >> 4;

    bf16x8 afr[4];
    int arow = r0 + m;
    bool rowok = arow < m_total;
    const uint4* v16 = (const uint4*)V;
    #pragma unroll
    for (int kc = 0; kc < 4; ++kc) {
        U4B8 a;
        if (rowok) a.q = v16[(size_t)arow * 16 + kc * 4 + quad];
        else { a.q.x = a.q.y = a.q.z = a.q.w = 0u; }
        afr[kc] = a.v;
    }
    float lv[4];
    #pragma unroll
    for (int t = 0; t < 4; ++t) {
        int r = r0 + quad * 4 + t;
        lv[t] = (r < m_total) ? Lbuf[r] : 0.f;
    }

    const uint4* wp = (const uint4*)WhP;
    #pragma unroll
    for (int nt = 0; nt < 3; ++nt) {
        f32x4 acc = {0.f, 0.f, 0.f, 0.f};
        #pragma unroll
        for (int kc = 0; kc < 4; ++kc) {
            U4B8 b; b.q = wp[(nt * 4 + kc) * 64 + lane];
            acc = __builtin_amdgcn_mfma_f32_16x16x32_bf16(afr[kc], b.v, acc, 0, 0, 0);
        }
        int colc = nt * 16 + m;
        if (colc < C) {
            float wsc = whs[colc], bc = bh[colc];
            #pragma unroll
            for (int t = 0; t < 4; ++t) {
                int r = r0 + quad * 4 + t;
                if (r < m_total)
                    outp[(size_t)r * C + colc] = acc[t] - lv[t] * wsc + bc;
            }
        }
    }
}

// ---------------------------------------------------------------------------
extern "C" void kernel_launch(void* const* d_in, const int* in_sizes, int n_in,
                              void* d_out, int out_size, void* d_ws, size_t ws_size,
                              hipStream_t stream) {
    const float* x      = (const float*)d_in[0];
    const int*   edges  = (const int*)d_in[1];
    const int*   labels = (const int*)d_in[2];
    const float* W0 = (const float*)d_in[3];
    const float* b0 = (const float*)d_in[4];
    const float* W1 = (const float*)d_in[5];
    const float* b1 = (const float*)d_in[6];
    const float* W2 = (const float*)d_in[7];
    const float* b2 = (const float*)d_in[8];
    const float* W3 = (const float*)d_in[9];
    const float* b3 = (const float*)d_in[10];
    const float* Wh = (const float*)d_in[11];
    const float* bh = (const float*)d_in[12];
    float* out = (float*)d_out;

    const int N = in_sizes[0] / DIM;       // 50000
    const int E = in_sizes[1] / 2;         // 600000
    const int M = in_sizes[2];             // 25000
    const int C = in_sizes[12];            // 40

    // Workspace layout (256B-aligned slices)
    char* ws = (char*)d_ws;
    auto alloc = [&](size_t bytes) {
        char* p = ws;
        ws += (bytes + 255) & ~(size_t)255;
        return p;
    };
    float* dinv    = (float*)alloc((size_t)N * 4);
    int*   count   = (int*)  alloc((size_t)N * 4);
    int*   row_ptr = (int*)  alloc((size_t)(N + 1) * 4);
    int*   cursor  = (int*)  alloc((size_t)N * 4);
    int*   partial = (int*)  alloc((size_t)N * 4);
    int*   bsum    = (int*)  alloc(64 * 4);
    int*   col     = (int*)  alloc((size_t)E * 4);
    float* whs     = (float*)alloc(256);
    unsigned short* Wpk = (unsigned short*)alloc((size_t)4 * DIM * DIM * 2); // packed W0..3
    unsigned short* WhP = (unsigned short*)alloc((size_t)3 * 4 * 64 * 8 * 2); // packed Wh
    unsigned short* H   = (unsigned short*)alloc((size_t)N * DIM * 2);       // bf16 H'
    unsigned short* R0  = (unsigned short*)alloc((size_t)N * DIM * 2);       // relu(cell0) bf16
    unsigned short* A   = (unsigned short*)alloc((size_t)N * DIM * 2);       // running relu-sum bf16
    unsigned short* V   = (unsigned short*)alloc((size_t)M * DIM * 2);       // cell3 rows bf16
    float* Lbuf         = (float*)alloc((size_t)M * 4);                      // logsumexp per row

    const int* src = edges;
    const int* dst = edges + E;

    int egrid  = (E + 255) / 256;
    int sgrid  = (N + 1023) / 1024;        // scan blocks (49 for N=50000)
    int mmgrid = (N + 63) / 64;            // 64-row strips, 4 waves/block
    int pgrid  = (N + 3) / 4;              // one wave per node, 4 waves/block
    const int FR = DIM * DIM;              // per-matrix packed elements
    const int NPACK = 4 * FR + 3 * 4 * 64 * 8 + 64;
    int packgrid = ((NPACK > N ? NPACK : N) + 255) / 256;

    // --- weight packing + count zeroing (one launch, replaces memset) ---
    k_pack <<<packgrid, 256, 0, stream>>>(W0, W1, W2, W3, Wh, Wpk, WhP, whs, count, C, N);
    // --- CSR build ---
    k_count<<<egrid, 256, 0, stream>>>(dst, count, E);
    k_scanA<<<sgrid, 1024, 0, stream>>>(count, partial, bsum, dinv, N);
    k_scanB<<<sgrid, 1024, 0, stream>>>(count, partial, bsum, row_ptr, cursor, N, sgrid);
    k_fill <<<egrid, 256, 0, stream>>>(src, dst, cursor, col, E);

    // --- R0 = relu(cell0) = relu(Â(x W0) + b0) ---
    k_matmul_f<<<mmgrid, 256, 0, stream>>>(x, Wpk + 0 * FR, dinv, H, N);
    k_prop    <<<pgrid, 256, 0, stream>>>(H, row_ptr, col, dinv, b0, 1.f, nullptr, R0, N);
    // --- A = R0 + relu(cell1),  cell1 = Â(R0 W1) + b1 ---
    k_matmul_b<<<mmgrid, 256, 0, stream>>>(R0, Wpk + 1 * FR, dinv, H, N);
    k_prop    <<<pgrid, 256, 0, stream>>>(H, row_ptr, col, dinv, b1, 1.f, R0, A, N);
    // --- A += relu(cell2),  cell2 = Â(A W2) + 2 b2  (in-place row-local) ---
    k_matmul_b<<<mmgrid, 256, 0, stream>>>(A, Wpk + 2 * FR, dinv, H, N);
    k_prop    <<<pgrid, 256, 0, stream>>>(H, row_ptr, col, dinv, b2, 2.f, A, A, N);
    // --- cell3 at label rows only -> V,L; then MFMA head GEMM ---
    k_matmul_b<<<mmgrid, 256, 0, stream>>>(A, Wpk + 3 * FR, dinv, H, N);
    k_prop_v  <<<(M + 3) / 4, 256, 0, stream>>>(H, row_ptr, col, dinv, b3, 3.f,
                                                labels, V, Lbuf, M);
    k_head    <<<(M + 63) / 64, 256, 0, stream>>>(V, Lbuf, WhP, whs, bh, out, M, C);
}

// Round 13
// 319.581 us; speedup vs baseline: 1.1074x; 1.1074x over previous
//
#include <hip/hip_runtime.h>
#include <hip/hip_bf16.h>
#include <cstdint>
#include <cstddef>

// Problem constants (from reference): N=50000, E=600000, D=128, C=40, M=25000
#define DIM 128

typedef __attribute__((ext_vector_type(8))) short bf16x8;   // 8 bf16 = 4 VGPRs
typedef __attribute__((ext_vector_type(4))) float f32x4;

__device__ __forceinline__ unsigned short f2bf(float f) {
    __hip_bfloat16 h = __float2bfloat16(f);   // RN-even
    return *(unsigned short*)&h;
}
__device__ __forceinline__ unsigned pack_bf2(float a, float b) {
    return (unsigned)f2bf(a) | ((unsigned)f2bf(b) << 16);
}
// dword holding 2 bf16 -> two fp32: lo = u<<16, hi = u & 0xffff0000
__device__ __forceinline__ float bflo(unsigned u) { return __uint_as_float(u << 16); }
__device__ __forceinline__ float bfhi(unsigned u) { return __uint_as_float(u & 0xffff0000u); }

union U4B8 { uint4 q; bf16x8 v; };

// ---------------------------------------------------------------------------
// CSR build: count in-degrees, parallel scan (+dinv fused), fill column lists
// ---------------------------------------------------------------------------
__global__ void k_count(const int* __restrict__ dst, int* __restrict__ count, int e) {
    int i = blockIdx.x * 256 + threadIdx.x;
    if (i < e) atomicAdd(&count[dst[i]], 1);
}

__global__ __launch_bounds__(1024)
void k_scanA(const int* __restrict__ count, int* __restrict__ partial,
             int* __restrict__ bsum, float* __restrict__ dinv, int n) {
    __shared__ int wsum[16];
    int tid = threadIdx.x, lane = tid & 63, wid = tid >> 6;
    int i = blockIdx.x * 1024 + tid;
    int v = (i < n) ? count[i] : 0;
    if (i < n) dinv[i] = rsqrtf(1.0f + (float)v);   // deg includes self-loop
    int x = v;
    #pragma unroll
    for (int off = 1; off < 64; off <<= 1) {
        int y = __shfl_up(x, off, 64);
        if (lane >= off) x += y;
    }
    if (lane == 63) wsum[wid] = x;
    __syncthreads();
    int waveoff = 0, total = 0;
    #pragma unroll
    for (int w = 0; w < 16; ++w) {
        int s = wsum[w];
        if (w < wid) waveoff += s;
        total += s;
    }
    if (i < n) partial[i] = x + waveoff;            // block-local inclusive
    if (tid == 0) bsum[blockIdx.x] = total;
}

__global__ __launch_bounds__(1024)
void k_scanB(const int* __restrict__ count, const int* __restrict__ partial,
             const int* __restrict__ bsum, int* __restrict__ row_ptr,
             int* __restrict__ cursor, int n, int nb) {
    __shared__ int s_off;
    int tid = threadIdx.x;
    if (tid < 64) {
        int carry = 0;
        for (int base = 0; base < nb; base += 64) {
            int idx = base + tid;
            int v = (idx < nb && idx < blockIdx.x) ? bsum[idx] : 0;
            #pragma unroll
            for (int off = 32; off > 0; off >>= 1) v += __shfl_xor(v, off, 64);
            carry += v;
        }
        if (tid == 0) s_off = carry;
    }
    __syncthreads();
    int off = s_off;
    int i = blockIdx.x * 1024 + tid;
    if (i < n) {
        int inc = partial[i] + off;
        row_ptr[i + 1] = inc;
        cursor[i] = inc - count[i];
    }
    if (blockIdx.x == 0 && tid == 0) row_ptr[0] = 0;
}

__global__ void k_fill(const int* __restrict__ src, const int* __restrict__ dst,
                       int* __restrict__ cursor, int* __restrict__ col, int e) {
    int i = blockIdx.x * 256 + threadIdx.x;
    if (i < e) {
        int d = dst[i];
        int pos = atomicAdd(&cursor[d], 1);
        col[pos] = src[i];
    }
}

// ---------------------------------------------------------------------------
// One-shot packing (merged: Wpk + WhP + whs, one launch).
// Wpk[(((mat*8+nt)*4+kc)*64 + lane)*8 + j] = bf16(W[k][n])
//   k = kc*32 + (lane>>4)*8 + j,  n = nt*16 + (lane&15).
// WhP: same frag order, 3 zero-padded n-tiles of Wh [128][C].
// whs: column sums of Wh.
// ---------------------------------------------------------------------------
__global__ void k_pack(const float* __restrict__ W0, const float* __restrict__ W1,
                       const float* __restrict__ W2, const float* __restrict__ W3,
                       const float* __restrict__ Wh,
                       unsigned short* __restrict__ Wpk,
                       unsigned short* __restrict__ WhP,
                       float* __restrict__ whs, int C) {
    const int NW = 4 * DIM * DIM;        // 65536
    const int NH = 3 * 4 * 64 * 8;       // 6144
    int g = blockIdx.x * 256 + threadIdx.x;
    if (g < NW) {
        int j   = g & 7;
        int ln  = (g >> 3) & 63;
        int kc  = (g >> 9) & 3;
        int nt  = (g >> 11) & 7;
        int mat = g >> 14;
        const float* W = (mat == 0) ? W0 : (mat == 1) ? W1 : (mat == 2) ? W2 : W3;
        int k = kc * 32 + (ln >> 4) * 8 + j;
        int nc = nt * 16 + (ln & 15);
        Wpk[g] = f2bf(W[k * DIM + nc]);
    } else if (g < NW + NH) {
        int gg = g - NW;
        int j  = gg & 7;
        int ln = (gg >> 3) & 63;
        int kc = (gg >> 9) & 3;
        int nt = gg >> 11;               // 0..2
        int k  = kc * 32 + (ln >> 4) * 8 + j;
        int nc = nt * 16 + (ln & 15);
        WhP[gg] = (nc < C) ? f2bf(Wh[k * C + nc]) : (unsigned short)0;
    } else if (g < NW + NH + 64) {
        int c = g - NW - NH;
        if (c < C) {
            float s = 0.f;
            for (int d = 0; d < DIM; ++d) s += Wh[d * C + c];
            whs[c] = s;
        }
    }
}

// ---------------------------------------------------------------------------
// MFMA matmul, fp32 input (layer 0): H'[N,128](bf16) = dinv[r]*(in @ W).
// Wave = 16-row x 128-col strip: 8 n-tiles x 4 kc = 32 mfma_f32_16x16x32_bf16.
// No LDS, no barriers. Layouts (m89/m91-verified).
// ---------------------------------------------------------------------------
__global__ __launch_bounds__(256)
void k_matmul_f(const float* __restrict__ in, const unsigned short* __restrict__ Wpk,
                const float* __restrict__ dinv, unsigned short* __restrict__ outp, int n) {
    int wv   = threadIdx.x >> 6;
    int lane = threadIdx.x & 63;
    int r0   = blockIdx.x * 64 + wv * 16;
    int m    = lane & 15;
    int quad = lane >> 4;

    bf16x8 afr[4];
    int arow = r0 + m;
    bool rowok = arow < n;
    const float* ap = in + (size_t)arow * DIM + quad * 8;
    #pragma unroll
    for (int kc = 0; kc < 4; ++kc) {
        float4 p0, p1;
        if (rowok) {
            p0 = *(const float4*)(ap + kc * 32);
            p1 = *(const float4*)(ap + kc * 32 + 4);
        } else {
            p0.x = p0.y = p0.z = p0.w = 0.f;
            p1.x = p1.y = p1.z = p1.w = 0.f;
        }
        union { bf16x8 v; unsigned short u[8]; } a;
        a.u[0] = f2bf(p0.x); a.u[1] = f2bf(p0.y);
        a.u[2] = f2bf(p0.z); a.u[3] = f2bf(p0.w);
        a.u[4] = f2bf(p1.x); a.u[5] = f2bf(p1.y);
        a.u[6] = f2bf(p1.z); a.u[7] = f2bf(p1.w);
        afr[kc] = a.v;
    }

    float dsc[4];
    #pragma unroll
    for (int t = 0; t < 4; ++t) {
        int r = r0 + quad * 4 + t;
        dsc[t] = (r < n) ? dinv[r] : 0.f;
    }

    const uint4* wp = (const uint4*)Wpk;
    #pragma unroll
    for (int nt = 0; nt < 8; ++nt) {
        f32x4 acc = {0.f, 0.f, 0.f, 0.f};
        #pragma unroll
        for (int kc = 0; kc < 4; ++kc) {
            U4B8 b; b.q = wp[(nt * 4 + kc) * 64 + lane];
            acc = __builtin_amdgcn_mfma_f32_16x16x32_bf16(afr[kc], b.v, acc, 0, 0, 0);
        }
        int colb = nt * 16 + m;
        #pragma unroll
        for (int t = 0; t < 4; ++t) {
            int r = r0 + quad * 4 + t;
            if (r < n)
                outp[(size_t)r * DIM + colb] = f2bf(dsc[t] * acc[t]);
        }
    }
}

// Same, bf16 input (layers 1-3): A-frag is a single uint4 load per K-chunk.
__global__ __launch_bounds__(256)
void k_matmul_b(const unsigned short* __restrict__ in, const unsigned short* __restrict__ Wpk,
                const float* __restrict__ dinv, unsigned short* __restrict__ outp, int n) {
    int wv   = threadIdx.x >> 6;
    int lane = threadIdx.x & 63;
    int r0   = blockIdx.x * 64 + wv * 16;
    int m    = lane & 15;
    int quad = lane >> 4;

    bf16x8 afr[4];
    int arow = r0 + m;
    bool rowok = arow < n;
    const uint4* in16 = (const uint4*)in;   // one row = 16 uint4
    #pragma unroll
    for (int kc = 0; kc < 4; ++kc) {
        U4B8 a;
        if (rowok) a.q = in16[(size_t)arow * 16 + kc * 4 + quad];
        else { a.q.x = a.q.y = a.q.z = a.q.w = 0u; }
        afr[kc] = a.v;
    }

    float dsc[4];
    #pragma unroll
    for (int t = 0; t < 4; ++t) {
        int r = r0 + quad * 4 + t;
        dsc[t] = (r < n) ? dinv[r] : 0.f;
    }

    const uint4* wp = (const uint4*)Wpk;
    #pragma unroll
    for (int nt = 0; nt < 8; ++nt) {
        f32x4 acc = {0.f, 0.f, 0.f, 0.f};
        #pragma unroll
        for (int kc = 0; kc < 4; ++kc) {
            U4B8 b; b.q = wp[(nt * 4 + kc) * 64 + lane];
            acc = __builtin_amdgcn_mfma_f32_16x16x32_bf16(afr[kc], b.v, acc, 0, 0, 0);
        }
        int colb = nt * 16 + m;
        #pragma unroll
        for (int t = 0; t < 4; ++t) {
            int r = r0 + quad * 4 + t;
            if (r < n)
                outp[(size_t)r * DIM + colb] = f2bf(dsc[t] * acc[t]);
        }
    }
}

// ---------------------------------------------------------------------------
// Propagation over pre-scaled bf16 H', quarter-wave gather, 2-deep pipeline:
// quarter q processes edge pairs (beg+q+8k, beg+q+4+8k); both uint4 row
// gathers issue back-to-back into separate accumulator banks, and the next
// pair's col indices load before accumulation (~4 outstanding loads/lane).
//   cell = di*(sum_edges H'[s] + H'[node]) + bscale*bias; relu; (+addin)
// addin==outp (in-place) allowed: each wave only touches its own row.
// [FINAL STRUCTURE. Deeper pipelining is a dead end, tested twice:
//  R10 4-deep hoisted self-row pre-shuffle -> 4x self-loop, absmax 18 (bug);
//  R12 4-deep fixed -> 354us vs 322us: 16-lane-granular exec-mask divergence
//  on the guarded loads + register pressure beat the MLP gain. At avg degree
//  12 (~3 edges/quarter) throughput comes from occupancy, not loads/wave.]
// ---------------------------------------------------------------------------
__global__ __launch_bounds__(256)
void k_prop(const unsigned short* __restrict__ h, const int* __restrict__ row_ptr,
            const int* __restrict__ col, const float* __restrict__ dinv,
            const float* __restrict__ bias, float bscale,
            const unsigned short* addin, unsigned short* outp, int n) {
    int node = (blockIdx.x * 256 + threadIdx.x) >> 6;
    int lane = threadIdx.x & 63;
    if (node >= n) return;
    int beg = row_ptr[node], end = row_ptr[node + 1];
    float di = dinv[node];
    int qid = lane >> 4;            // which quarter
    int fo  = lane & 15;            // feature octet: features 8*fo .. 8*fo+7
    const uint4* h16 = (const uint4*)h;   // one row = 16 uint4
    float aL0 = 0.f, aH0 = 0.f, aL1 = 0.f, aH1 = 0.f;
    float aL2 = 0.f, aH2 = 0.f, aL3 = 0.f, aH3 = 0.f;
    float bL0 = 0.f, bH0 = 0.f, bL1 = 0.f, bH1 = 0.f;
    float bL2 = 0.f, bH2 = 0.f, bL3 = 0.f, bH3 = 0.f;
    int j = beg + qid;
    int s0 = (j < end) ? col[j] : -1;
    int s1 = (j + 4 < end) ? col[j + 4] : -1;
    while (s0 >= 0) {
        uint4 d0 = h16[((unsigned)s0 << 4) | fo];
        uint4 d1 = {0u, 0u, 0u, 0u};
        if (s1 >= 0) d1 = h16[((unsigned)s1 << 4) | fo];
        int jn = j + 8;
        s0 = (jn < end) ? col[jn] : -1;          // prefetch next pair
        s1 = (jn + 4 < end) ? col[jn + 4] : -1;
        j = jn;
        aL0 += bflo(d0.x); aH0 += bfhi(d0.x);
        aL1 += bflo(d0.y); aH1 += bfhi(d0.y);
        aL2 += bflo(d0.z); aH2 += bfhi(d0.z);
        aL3 += bflo(d0.w); aH3 += bfhi(d0.w);
        bL0 += bflo(d1.x); bH0 += bfhi(d1.x);    // zeros when pair absent
        bL1 += bflo(d1.y); bH1 += bfhi(d1.y);
        bL2 += bflo(d1.z); bH2 += bfhi(d1.z);
        bL3 += bflo(d1.w); bH3 += bfhi(d1.w);
    }
    aL0 += bL0; aH0 += bH0; aL1 += bL1; aH1 += bH1;
    aL2 += bL2; aH2 += bH2; aL3 += bL3; aH3 += bH3;
    // combine the 4 quarters (wave fully reconverged here)
    aL0 += __shfl_xor(aL0, 16, 64); aL0 += __shfl_xor(aL0, 32, 64);
    aH0 += __shfl_xor(aH0, 16, 64); aH0 += __shfl_xor(aH0, 32, 64);
    aL1 += __shfl_xor(aL1, 16, 64); aL1 += __shfl_xor(aL1, 32, 64);
    aH1 += __shfl_xor(aH1, 16, 64); aH1 += __shfl_xor(aH1, 32, 64);
    aL2 += __shfl_xor(aL2, 16, 64); aL2 += __shfl_xor(aL2, 32, 64);
    aH2 += __shfl_xor(aH2, 16, 64); aH2 += __shfl_xor(aH2, 32, 64);
    aL3 += __shfl_xor(aL3, 16, 64); aL3 += __shfl_xor(aL3, 32, 64);
    aH3 += __shfl_xor(aH3, 16, 64); aH3 += __shfl_xor(aH3, 32, 64);
    // self-loop: di^2*h[node] = di * H'[node]  (added once, post-reduction)
    uint4 sd = h16[((unsigned)node << 4) | fo];
    aL0 += bflo(sd.x); aH0 += bfhi(sd.x);
    aL1 += bflo(sd.y); aH1 += bfhi(sd.y);
    aL2 += bflo(sd.z); aH2 += bfhi(sd.z);
    aL3 += bflo(sd.w); aH3 += bfhi(sd.w);
    if (lane < 16) {                // fo lanes of quarter 0 store the row
        const float4* b4 = (const float4*)bias;
        float4 bA = b4[2 * fo], bB = b4[2 * fo + 1];
        float r0x = fmaxf(fmaf(bscale, bA.x, di * aL0), 0.f);
        float r0y = fmaxf(fmaf(bscale, bA.y, di * aH0), 0.f);
        float r0z = fmaxf(fmaf(bscale, bA.z, di * aL1), 0.f);
        float r0w = fmaxf(fmaf(bscale, bA.w, di * aH1), 0.f);
        float r1x = fmaxf(fmaf(bscale, bB.x, di * aL2), 0.f);
        float r1y = fmaxf(fmaf(bscale, bB.y, di * aH2), 0.f);
        float r1z = fmaxf(fmaf(bscale, bB.z, di * aL3), 0.f);
        float r1w = fmaxf(fmaf(bscale, bB.w, di * aH3), 0.f);
        size_t base = (size_t)node * 16 + fo;
        if (addin) {
            uint4 av = ((const uint4*)addin)[base];
            r0x += bflo(av.x); r0y += bfhi(av.x);
            r0z += bflo(av.y); r0w += bfhi(av.y);
            r1x += bflo(av.z); r1y += bfhi(av.z);
            r1z += bflo(av.w); r1w += bfhi(av.w);
        }
        uint4 o;
        o.x = pack_bf2(r0x, r0y);
        o.y = pack_bf2(r0z, r0w);
        o.z = pack_bf2(r1x, r1y);
        o.w = pack_bf2(r1z, r1w);
        ((uint4*)outp)[base] = o;
    }
}

// ---------------------------------------------------------------------------
// Gather cell3 for label rows only; same 2-deep pipelined gather; writes
// compact bf16 V[m,128] + L[m] (logsumexp). Head matmul in k_head (MFMA).
// ---------------------------------------------------------------------------
__global__ __launch_bounds__(256)
void k_prop_v(const unsigned short* __restrict__ h, const int* __restrict__ row_ptr,
              const int* __restrict__ col, const float* __restrict__ dinv,
              const float* __restrict__ bias, float bscale,
              const int* __restrict__ labels,
              unsigned short* __restrict__ V, float* __restrict__ Lbuf, int m_total) {
    int m = (blockIdx.x * 256 + threadIdx.x) >> 6;
    int lane = threadIdx.x & 63;
    if (m >= m_total) return;
    int node = labels[m];
    int beg = row_ptr[node], end = row_ptr[node + 1];
    float di = dinv[node];
    int qid = lane >> 4, fo = lane & 15;
    const uint4* h16 = (const uint4*)h;
    float aL0 = 0.f, aH0 = 0.f, aL1 = 0.f, aH1 = 0.f;
    float aL2 = 0.f, aH2 = 0.f, aL3 = 0.f, aH3 = 0.f;
    float bL0 = 0.f, bH0 = 0.f, bL1 = 0.f, bH1 = 0.f;
    float bL2 = 0.f, bH2 = 0.f, bL3 = 0.f, bH3 = 0.f;
    int j = beg + qid;
    int s0 = (j < end) ? col[j] : -1;
    int s1 = (j + 4 < end) ? col[j + 4] : -1;
    while (s0 >= 0) {
        uint4 d0 = h16[((unsigned)s0 << 4) | fo];
        uint4 d1 = {0u, 0u, 0u, 0u};
        if (s1 >= 0) d1 = h16[((unsigned)s1 << 4) | fo];
        int jn = j + 8;
        s0 = (jn < end) ? col[jn] : -1;
        s1 = (jn + 4 < end) ? col[jn + 4] : -1;
        j = jn;
        aL0 += bflo(d0.x); aH0 += bfhi(d0.x);
        aL1 += bflo(d0.y); aH1 += bfhi(d0.y);
        aL2 += bflo(d0.z); aH2 += bfhi(d0.z);
        aL3 += bflo(d0.w); aH3 += bfhi(d0.w);
        bL0 += bflo(d1.x); bH0 += bfhi(d1.x);
        bL1 += bflo(d1.y); bH1 += bfhi(d1.y);
        bL2 += bflo(d1.z); bH2 += bfhi(d1.z);
        bL3 += bflo(d1.w); bH3 += bfhi(d1.w);
    }
    aL0 += bL0; aH0 += bH0; aL1 += bL1; aH1 += bH1;
    aL2 += bL2; aH2 += bH2; aL3 += bL3; aH3 += bH3;
    aL0 += __shfl_xor(aL0, 16, 64); aL0 += __shfl_xor(aL0, 32, 64);
    aH0 += __shfl_xor(aH0, 16, 64); aH0 += __shfl_xor(aH0, 32, 64);
    aL1 += __shfl_xor(aL1, 16, 64); aL1 += __shfl_xor(aL1, 32, 64);
    aH1 += __shfl_xor(aH1, 16, 64); aH1 += __shfl_xor(aH1, 32, 64);
    aL2 += __shfl_xor(aL2, 16, 64); aL2 += __shfl_xor(aL2, 32, 64);
    aH2 += __shfl_xor(aH2, 16, 64); aH2 += __shfl_xor(aH2, 32, 64);
    aL3 += __shfl_xor(aL3, 16, 64); aL3 += __shfl_xor(aL3, 32, 64);
    aH3 += __shfl_xor(aH3, 16, 64); aH3 += __shfl_xor(aH3, 32, 64);
    uint4 sd = h16[((unsigned)node << 4) | fo];
    aL0 += bflo(sd.x); aH0 += bfhi(sd.x);
    aL1 += bflo(sd.y); aH1 += bfhi(sd.y);
    aL2 += bflo(sd.z); aH2 += bfhi(sd.z);
    aL3 += bflo(sd.w); aH3 += bfhi(sd.w);
    const float4* b4 = (const float4*)bias;
    float4 bA = b4[2 * fo], bB = b4[2 * fo + 1];
    float v0 = fmaf(bscale, bA.x, di * aL0);
    float v1 = fmaf(bscale, bA.y, di * aH0);
    float v2 = fmaf(bscale, bA.z, di * aL1);
    float v3 = fmaf(bscale, bA.w, di * aH1);
    float v4 = fmaf(bscale, bB.x, di * aL2);
    float v5 = fmaf(bscale, bB.y, di * aH2);
    float v6 = fmaf(bscale, bB.z, di * aL3);
    float v7 = fmaf(bscale, bB.w, di * aH3);
    // logsumexp over 128 features (16 distinct fo groups; quarters duplicate)
    float mx = fmaxf(fmaxf(fmaxf(v0, v1), fmaxf(v2, v3)),
                     fmaxf(fmaxf(v4, v5), fmaxf(v6, v7)));
    #pragma unroll
    for (int off = 8; off > 0; off >>= 1) mx = fmaxf(mx, __shfl_xor(mx, off, 64));
    float se = expf(v0 - mx) + expf(v1 - mx) + expf(v2 - mx) + expf(v3 - mx)
             + expf(v4 - mx) + expf(v5 - mx) + expf(v6 - mx) + expf(v7 - mx);
    #pragma unroll
    for (int off = 8; off > 0; off >>= 1) se += __shfl_xor(se, off, 64);
    float L = mx + logf(se);
    if (lane < 16) {
        uint4 o;
        o.x = pack_bf2(v0, v1);
        o.y = pack_bf2(v2, v3);
        o.z = pack_bf2(v4, v5);
        o.w = pack_bf2(v6, v7);
        ((uint4*)V)[(size_t)m * 16 + fo] = o;
    }
    if (lane == 0) Lbuf[m] = L;
}

// ---------------------------------------------------------------------------
// Head GEMM (MFMA): out[m,c] = V[m,:]@Wh[:,c] - L[m]*whs[c] + bh[c], c<C.
// Wave = 16 rows; 3 n-tiles (48 padded cols) x 4 kc = 12 MFMAs.
// ---------------------------------------------------------------------------
__global__ __launch_bounds__(256)
void k_head(const unsigned short* __restrict__ V, const float* __restrict__ Lbuf,
            const unsigned short* __restrict__ WhP, const float* __restrict__ whs,
            const float* __restrict__ bh, float* __restrict__ outp,
            int m_total, int C) {
    int wv   = threadIdx.x >> 6;
    int lane = threadIdx.x & 63;
    int r0   = blockIdx.x * 64 + wv * 16;
    int m    = lane & 15;
    int quad = lane >> 4;

    bf16x8 afr[4];
    int arow = r0 + m;
    bool rowok = arow < m_total;
    const uint4* v16 = (const uint4*)V;
    #pragma unroll
    for (int kc = 0; kc < 4; ++kc) {
        U4B8 a;
        if (rowok) a.q = v16[(size_t)arow * 16 + kc * 4 + quad];
        else { a.q.x = a.q.y = a.q.z = a.q.w = 0u; }
        afr[kc] = a.v;
    }
    float lv[4];
    #pragma unroll
    for (int t = 0; t < 4; ++t) {
        int r = r0 + quad * 4 + t;
        lv[t] = (r < m_total) ? Lbuf[r] : 0.f;
    }

    const uint4* wp = (const uint4*)WhP;
    #pragma unroll
    for (int nt = 0; nt < 3; ++nt) {
        f32x4 acc = {0.f, 0.f, 0.f, 0.f};
        #pragma unroll
        for (int kc = 0; kc < 4; ++kc) {
            U4B8 b; b.q = wp[(nt * 4 + kc) * 64 + lane];
            acc = __builtin_amdgcn_mfma_f32_16x16x32_bf16(afr[kc], b.v, acc, 0, 0, 0);
        }
        int colc = nt * 16 + m;
        if (colc < C) {
            float wsc = whs[colc], bc = bh[colc];
            #pragma unroll
            for (int t = 0; t < 4; ++t) {
                int r = r0 + quad * 4 + t;
                if (r < m_total)
                    outp[(size_t)r * C + colc] = acc[t] - lv[t] * wsc + bc;
            }
        }
    }
}

// ---------------------------------------------------------------------------
extern "C" void kernel_launch(void* const* d_in, const int* in_sizes, int n_in,
                              void* d_out, int out_size, void* d_ws, size_t ws_size,
                              hipStream_t stream) {
    const float* x      = (const float*)d_in[0];
    const int*   edges  = (const int*)d_in[1];
    const int*   labels = (const int*)d_in[2];
    const float* W0 = (const float*)d_in[3];
    const float* b0 = (const float*)d_in[4];
    const float* W1 = (const float*)d_in[5];
    const float* b1 = (const float*)d_in[6];
    const float* W2 = (const float*)d_in[7];
    const float* b2 = (const float*)d_in[8];
    const float* W3 = (const float*)d_in[9];
    const float* b3 = (const float*)d_in[10];
    const float* Wh = (const float*)d_in[11];
    const float* bh = (const float*)d_in[12];
    float* out = (float*)d_out;

    const int N = in_sizes[0] / DIM;       // 50000
    const int E = in_sizes[1] / 2;         // 600000
    const int M = in_sizes[2];             // 25000
    const int C = in_sizes[12];            // 40

    // Workspace layout (256B-aligned slices)
    char* ws = (char*)d_ws;
    auto alloc = [&](size_t bytes) {
        char* p = ws;
        ws += (bytes + 255) & ~(size_t)255;
        return p;
    };
    float* dinv    = (float*)alloc((size_t)N * 4);
    int*   count   = (int*)  alloc((size_t)N * 4);
    int*   row_ptr = (int*)  alloc((size_t)(N + 1) * 4);
    int*   cursor  = (int*)  alloc((size_t)N * 4);
    int*   partial = (int*)  alloc((size_t)N * 4);
    int*   bsum    = (int*)  alloc(64 * 4);
    int*   col     = (int*)  alloc((size_t)E * 4);
    float* whs     = (float*)alloc(256);
    unsigned short* Wpk = (unsigned short*)alloc((size_t)4 * DIM * DIM * 2); // packed W0..3
    unsigned short* WhP = (unsigned short*)alloc((size_t)3 * 4 * 64 * 8 * 2); // packed Wh
    unsigned short* H   = (unsigned short*)alloc((size_t)N * DIM * 2);       // bf16 H'
    unsigned short* R0  = (unsigned short*)alloc((size_t)N * DIM * 2);       // relu(cell0) bf16
    unsigned short* A   = (unsigned short*)alloc((size_t)N * DIM * 2);       // running relu-sum bf16
    unsigned short* V   = (unsigned short*)alloc((size_t)M * DIM * 2);       // cell3 rows bf16
    float* Lbuf         = (float*)alloc((size_t)M * 4);                      // logsumexp per row

    const int* src = edges;
    const int* dst = edges + E;

    int egrid  = (E + 255) / 256;
    int sgrid  = (N + 1023) / 1024;        // scan blocks (49 for N=50000)
    int mmgrid = (N + 63) / 64;            // 64-row strips, 4 waves/block
    int pgrid  = (N + 3) / 4;              // one wave per node, 4 waves/block
    const int FR = DIM * DIM;              // per-matrix packed elements
    const int NPACK = 4 * FR + 3 * 4 * 64 * 8 + 64;

    // --- CSR build + weight packing ---
    hipMemsetAsync(count, 0, (size_t)N * 4, stream);
    k_count<<<egrid, 256, 0, stream>>>(dst, count, E);
    k_scanA<<<sgrid, 1024, 0, stream>>>(count, partial, bsum, dinv, N);
    k_scanB<<<sgrid, 1024, 0, stream>>>(count, partial, bsum, row_ptr, cursor, N, sgrid);
    k_fill <<<egrid, 256, 0, stream>>>(src, dst, cursor, col, E);
    k_pack <<<(NPACK + 255) / 256, 256, 0, stream>>>(W0, W1, W2, W3, Wh, Wpk, WhP, whs, C);

    // --- R0 = relu(cell0) = relu(Â(x W0) + b0) ---
    k_matmul_f<<<mmgrid, 256, 0, stream>>>(x, Wpk + 0 * FR, dinv, H, N);
    k_prop    <<<pgrid, 256, 0, stream>>>(H, row_ptr, col, dinv, b0, 1.f, nullptr, R0, N);
    // --- A = R0 + relu(cell1),  cell1 = Â(R0 W1) + b1 ---
    k_matmul_b<<<mmgrid, 256, 0, stream>>>(R0, Wpk + 1 * FR, dinv, H, N);
    k_prop    <<<pgrid, 256, 0, stream>>>(H, row_ptr, col, dinv, b1, 1.f, R0, A, N);
    // --- A += relu(cell2),  cell2 = Â(A W2) + 2 b2  (in-place row-local) ---
    k_matmul_b<<<mmgrid, 256, 0, stream>>>(A, Wpk + 2 * FR, dinv, H, N);
    k_prop    <<<pgrid, 256, 0, stream>>>(H, row_ptr, col, dinv, b2, 2.f, A, A, N);
    // --- cell3 at label rows only -> V,L; then MFMA head GEMM ---
    k_matmul_b<<<mmgrid, 256, 0, stream>>>(A, Wpk + 3 * FR, dinv, H, N);
    k_prop_v  <<<(M + 3) / 4, 256, 0, stream>>>(H, row_ptr, col, dinv, b3, 3.f,
                                                labels, V, Lbuf, M);
    k_head    <<<(M + 63) / 64, 256, 0, stream>>>(V, Lbuf, WhP, whs, bh, out, M, C);
}